// Round 3
// baseline (417.262 us; speedup 1.0000x reference)
//
#include <hip/hip_runtime.h>
#include <cstdint>

// selected mean pool: for each (b,c,h,w), mean of x over the 25 taps
// (5x5, dilation 2, reflect pad 4) whose mask value equals the center mask.
//
// R3 design: NO LDS, NO barriers. Match bits computed once per (b,h) block,
// reused across all 64 channels. Each lane owns 4 px; its 12-float window per
// row = 3 overlapping float4 global loads (L1 serves the overlap); reflect
// boundary patched from registers on lanes 0/63 (reflected cols are already
// in f0/f1/f2). Rows software-pipelined. 8 waves/SIMD, all blocks resident.

#define B_ 8
#define C_ 64
#define H_ 256
#define W_ 256
#define NHW (H_ * W_)

__device__ __forceinline__ int reflect_i(int v, int n) {
  v = v < 0 ? -v : v;
  return v >= n ? 2 * n - 2 - v : v;
}

__global__ __launch_bounds__(256, 8)
void selected_meanpool_kernel(const float* __restrict__ x,
                              const float* __restrict__ mask,
                              float* __restrict__ out) {
  const int bid  = blockIdx.x;   // 0..2047
  const int b    = bid & 7;      // batch pinned to XCD: row reuse in that L2
  const int h    = bid >> 3;     // output row (wave-uniform -> hre in SGPRs)
  const int tid  = threadIdx.x;
  const int wv   = tid >> 6;     // wave 0..3
  const int lane = tid & 63;
  const int w0   = lane << 2;    // 4 px per lane covers W=256

  int hre[5];
#pragma unroll
  for (int r = 0; r < 5; ++r) hre[r] = reflect_i(h + 2 * r - 4, H_);

  // ---------- prologue: 25-bit match mask + 1/cnt per pixel (once) ----------
  const float* mb = mask + b * NHW;
  float4 mc4 = *(const float4*)&mb[h * W_ + w0];
  float mcv[4] = {mc4.x, mc4.y, mc4.z, mc4.w};

  uint32_t bits[4] = {0u, 0u, 0u, 0u};
#pragma unroll
  for (int r = 0; r < 5; ++r) {
    const float* mrow = mb + hre[r] * W_;
    // window cols w0-4 .. w0+7 via 3 overlapping float4 (clamped at edges)
    float4 f0 = *(const float4*)&mrow[lane == 0 ? 0 : w0 - 4];
    float4 f1 = *(const float4*)&mrow[w0];
    float4 f2 = *(const float4*)&mrow[lane == 63 ? 252 : w0 + 4];
    // reflect patch from registers: cols -4..-1 -> 4,3,2,1 ; 256..259 -> 254,253,252,251
    if (lane == 0)  { f0.x = f2.x; f0.y = f1.w; f0.z = f1.z; f0.w = f1.y; }
    if (lane == 63) { f2.x = f1.z; f2.y = f1.y; f2.z = f1.x; f2.w = f0.w; }
    float win[12] = {f0.x, f0.y, f0.z, f0.w,
                     f1.x, f1.y, f1.z, f1.w,
                     f2.x, f2.y, f2.z, f2.w};
#pragma unroll
    for (int jc = 0; jc < 5; ++jc)
#pragma unroll
      for (int p = 0; p < 4; ++p)
        if (win[p + 2 * jc] == mcv[p]) bits[p] |= (1u << (r * 5 + jc));
  }
  // center tap always matches -> cnt >= 1
  float inv[4];
#pragma unroll
  for (int p = 0; p < 4; ++p) inv[p] = 1.0f / (float)__builtin_popcount(bits[p]);

  const float* xb = x + (size_t)b * C_ * NHW;
  float*       ob = out + (size_t)b * C_ * NHW;

  // ---------- channel loop: wave wv does c = 4*ci + wv, no sync ----------
  for (int ci = 0; ci < 16; ++ci) {
    const int c = 4 * ci + wv;
    const float* xc = xb + (size_t)c * NHW;
    float acc[4] = {0.f, 0.f, 0.f, 0.f};

    // software pipeline: row r+1 loads in flight while accumulating row r
    const float* row0 = xc + hre[0] * W_;
    float4 f0 = *(const float4*)&row0[lane == 0 ? 0 : w0 - 4];
    float4 f1 = *(const float4*)&row0[w0];
    float4 f2 = *(const float4*)&row0[lane == 63 ? 252 : w0 + 4];
#pragma unroll
    for (int r = 0; r < 5; ++r) {
      float4 g0, g1, g2;
      if (r < 4) {
        const float* nrow = xc + hre[r + 1] * W_;
        g0 = *(const float4*)&nrow[lane == 0 ? 0 : w0 - 4];
        g1 = *(const float4*)&nrow[w0];
        g2 = *(const float4*)&nrow[lane == 63 ? 252 : w0 + 4];
      }
      if (lane == 0)  { f0.x = f2.x; f0.y = f1.w; f0.z = f1.z; f0.w = f1.y; }
      if (lane == 63) { f2.x = f1.z; f2.y = f1.y; f2.z = f1.x; f2.w = f0.w; }
      float win[12] = {f0.x, f0.y, f0.z, f0.w,
                       f1.x, f1.y, f1.z, f1.w,
                       f2.x, f2.y, f2.z, f2.w};
#pragma unroll
      for (int jc = 0; jc < 5; ++jc) {
        const int t = r * 5 + jc;
#pragma unroll
        for (int p = 0; p < 4; ++p) {
          // m = 0 or 0xFFFFFFFF from bit t of bits[p] -> and + add
#if __has_builtin(__builtin_amdgcn_sbfe)
          int m = __builtin_amdgcn_sbfe((int)bits[p], t, 1);
#else
          int m = ((int)(bits[p] << (31 - t))) >> 31;
#endif
          acc[p] += __int_as_float(__float_as_int(win[p + 2 * jc]) & m);
        }
      }
      if (r < 4) { f0 = g0; f1 = g1; f2 = g2; }
    }
    float4 o;
    o.x = acc[0] * inv[0];
    o.y = acc[1] * inv[1];
    o.z = acc[2] * inv[2];
    o.w = acc[3] * inv[3];
    *(float4*)&ob[(size_t)c * NHW + h * W_ + w0] = o;
  }
}

extern "C" void kernel_launch(void* const* d_in, const int* in_sizes, int n_in,
                              void* d_out, int out_size, void* d_ws, size_t ws_size,
                              hipStream_t stream) {
  const float* x    = (const float*)d_in[0];
  const float* mask = (const float*)d_in[1];
  float*       out  = (float*)d_out;
  dim3 grid(B_ * H_);   // one block per (b,h) output row
  dim3 block(256);      // 4 waves: 64 lanes x 4 px; wave -> channel slice
  hipLaunchKernelGGL(selected_meanpool_kernel, grid, block, 0, stream,
                     x, mask, out);
}

// Round 4
// 287.274 us; speedup vs baseline: 1.4525x; 1.4525x over previous
//
#include <hip/hip_runtime.h>
#include <cstdint>

// selected mean pool: for each (b,c,h,w), mean of x over the 25 taps
// (5x5, dilation 2, reflect pad 4) whose mask value equals the center mask.
//
// R4: back to R2's phase-synchronized LDS structure (barriers keep all blocks
// marching through the same 4-channel group -> inter-block row reuse hits
// L2/L3, FETCH ~69MB proven). Changes vs R2:
//   - __launch_bounds__(256,7): regalloc for 7 waves/EU (LDS allows 7 blk/CU)
//   - main-row staging via __builtin_amdgcn_global_load_lds (16B/lane, direct
//     HBM->LDS, no VGPR roundtrip, no ds_write): m97 pattern
// Math/halo/tap loop byte-identical to R2 (absmax was 0.0).

#define B_ 8
#define C_ 64
#define H_ 256
#define W_ 256
#define NHW (H_ * W_)

__device__ __forceinline__ int reflect_i(int v, int n) {
  v = v < 0 ? -v : v;
  return v >= n ? 2 * n - 2 - v : v;
}

__global__ __launch_bounds__(256, 7)
void selected_meanpool_kernel(const float* __restrict__ x,
                              const float* __restrict__ mask,
                              float* __restrict__ out) {
  // 4 channels x 5 rows x (256 + 8 halo) floats = 21120 B -> 7 blocks/CU
  __shared__ float smem[4][5][264];

  const int bid  = blockIdx.x;      // 0..2047
  const int b    = bid & 7;         // batch pinned to XCD: row reuse in its L2
  const int h    = bid >> 3;        // output row (wave-uniform)
  const int tid  = threadIdx.x;
  const int wv   = tid >> 6;        // wave 0..3
  const int lane = tid & 63;
  const int w0   = lane << 2;       // 4 px per lane covers W=256

  int hre[5];
#pragma unroll
  for (int r = 0; r < 5; ++r) hre[r] = reflect_i(h + 2 * r - 4, H_);

  // ---------- prologue: 25-bit match mask + 1/cnt per pixel (once) ----------
  const float* mb = mask + b * NHW;
  float mc[4];
#pragma unroll
  for (int p = 0; p < 4; ++p) mc[p] = mb[h * W_ + w0 + p];

  int wre[4][5];
#pragma unroll
  for (int p = 0; p < 4; ++p)
#pragma unroll
    for (int jc = 0; jc < 5; ++jc)
      wre[p][jc] = reflect_i(w0 + p + 2 * jc - 4, W_);

  uint32_t bits[4] = {0u, 0u, 0u, 0u};
#pragma unroll
  for (int r = 0; r < 5; ++r) {
    const float* mrow = mb + hre[r] * W_;
#pragma unroll
    for (int jc = 0; jc < 5; ++jc) {
#pragma unroll
      for (int p = 0; p < 4; ++p) {
        float mv = mrow[wre[p][jc]];
        if (mv == mc[p]) bits[p] |= (1u << (r * 5 + jc));
      }
    }
  }
  float inv[4];
#pragma unroll
  for (int p = 0; p < 4; ++p) inv[p] = 1.0f / (float)__builtin_popcount(bits[p]);

  const float* xb = x + (size_t)b * C_ * NHW;
  float*       ob = out + (size_t)b * C_ * NHW;

  for (int g = 0; g < 16; ++g) {
    // ---------- stage 4 channels x 5 rows: direct HBM->LDS, 16B per lane ----
#pragma unroll
    for (int k = 0; k < 5; ++k) {
      int pair = 4 * k + wv;            // wave-uniform: 20 (ch,row) pairs
      int cl = pair / 5, r = pair % 5;
      const float* src = xb + (4 * g + cl) * NHW + hre[r] * W_ + (lane << 2);
      // dest is WAVE-UNIFORM base; HW writes lane l at base + 16*l (linear)
      __builtin_amdgcn_global_load_lds(
          (const __attribute__((address_space(1))) void*)src,
          (__attribute__((address_space(3))) void*)&smem[cl][r][4],
          16, 0, 0);
    }
    // w-halo with reflect baked in: idx 0..3 = cols -4..-1, 260..263 = 256..259
    if (tid < 160) {
      int hp = tid >> 3, l3 = tid & 7;
      int cl = hp / 5, r = hp % 5;
      const float* rowp = xb + (4 * g + cl) * NHW + hre[r] * W_;
      if (l3 < 4) smem[cl][r][l3]       = rowp[4 - l3];     // reflect(l3-4)
      else        smem[cl][r][256 + l3] = rowp[258 - l3];   // reflect(252+l3)
    }
    __syncthreads();   // compiler drains vmcnt/lgkmcnt here (m97 pattern)

    // ---------- compute: wave wv handles channel c = 4g+wv ----------
    float acc[4] = {0.f, 0.f, 0.f, 0.f};
#pragma unroll
    for (int r = 0; r < 5; ++r) {
      float4 f0 = *(const float4*)&smem[wv][r][w0];
      float4 f1 = *(const float4*)&smem[wv][r][w0 + 4];
      float4 f2 = *(const float4*)&smem[wv][r][w0 + 8];
      float win[12] = {f0.x, f0.y, f0.z, f0.w,
                       f1.x, f1.y, f1.z, f1.w,
                       f2.x, f2.y, f2.z, f2.w};
#pragma unroll
      for (int jc = 0; jc < 5; ++jc) {
        const int t = r * 5 + jc;
#pragma unroll
        for (int p = 0; p < 4; ++p) {
#if __has_builtin(__builtin_amdgcn_sbfe)
          int m = __builtin_amdgcn_sbfe((int)bits[p], t, 1);
#else
          int m = ((int)(bits[p] << (31 - t))) >> 31;
#endif
          acc[p] += __int_as_float(__float_as_int(win[p + 2 * jc]) & m);
        }
      }
    }
    float4 o;
    o.x = acc[0] * inv[0];
    o.y = acc[1] * inv[1];
    o.z = acc[2] * inv[2];
    o.w = acc[3] * inv[3];
    *(float4*)&ob[(4 * g + wv) * NHW + h * W_ + w0] = o;
    __syncthreads();  // protect smem before next group's stage
  }
}

extern "C" void kernel_launch(void* const* d_in, const int* in_sizes, int n_in,
                              void* d_out, int out_size, void* d_ws, size_t ws_size,
                              hipStream_t stream) {
  const float* x    = (const float*)d_in[0];
  const float* mask = (const float*)d_in[1];
  float*       out  = (float*)d_out;
  dim3 grid(B_ * H_);   // one block per (b,h) output row
  dim3 block(256);      // 4 waves: 64 lanes x 4 px; wave -> channel of group
  hipLaunchKernelGGL(selected_meanpool_kernel, grid, block, 0, stream,
                     x, mask, out);
}